// Round 1
// baseline (447.071 us; speedup 1.0000x reference)
//
#include <hip/hip_runtime.h>
#include <hip/hip_bf16.h>

typedef float f32x4 __attribute__((ext_vector_type(4)));
typedef __bf16 bf16x8 __attribute__((ext_vector_type(8)));
typedef __bf16 bf16x4 __attribute__((ext_vector_type(4)));

constexpr int B_ = 2, T_ = 2048, C_ = 2048, H_ = 16, D_ = 128;
constexpr int M_ = B_ * T_;        // 4096
constexpr int NQKV_ = 3 * C_;      // 6144

// ---------------- fp32 -> bf16 convert (vectorized) ----------------
__global__ void cvt_kernel(const float* __restrict__ in, __bf16* __restrict__ out, int n4) {
    int i = blockIdx.x * blockDim.x + threadIdx.x;
    int stride = gridDim.x * blockDim.x;
    for (; i < n4; i += stride) {
        float4 v = reinterpret_cast<const float4*>(in)[i];
        bf16x4 o;
        o[0] = (__bf16)v.x; o[1] = (__bf16)v.y; o[2] = (__bf16)v.z; o[3] = (__bf16)v.w;
        reinterpret_cast<bf16x4*>(out)[i] = o;
    }
}

// ---------------- GEMM: C[M,N] = A[M,K] * B[N,K]^T (both row-major, bf16 in, OutT out) ----------------
template <typename OutT>
__global__ __launch_bounds__(256, 3) void gemm_bt(
    const __bf16* __restrict__ A, const __bf16* __restrict__ Bm,
    OutT* __restrict__ Cm, int Mdim, int Ndim, int Kdim)
{
    constexpr int BK = 64;
    __shared__ __align__(16) __bf16 As[128 * BK];
    __shared__ __align__(16) __bf16 Bs[128 * BK];
    const int tid = threadIdx.x;
    const int wave = tid >> 6, lane = tid & 63;
    const int fr = lane & 15, fq = lane >> 4;
    const int nbx = Ndim >> 7;
    const int bm = (blockIdx.x / nbx) << 7;
    const int bn = (blockIdx.x % nbx) << 7;
    const int wr = (wave >> 1) * 64, wc = (wave & 1) * 64;
    f32x4 acc[4][4] = {};
    const int srow = tid >> 3;   // 0..31
    const int schunk = tid & 7;  // 0..7  (16B chunks of a 128B row)

    for (int k0 = 0; k0 < Kdim; k0 += BK) {
        __syncthreads();
        #pragma unroll
        for (int p = 0; p < 4; ++p) {
            int r = p * 32 + srow;
            bf16x8 av = *reinterpret_cast<const bf16x8*>(A + (size_t)(bm + r) * Kdim + k0 + schunk * 8);
            bf16x8 bv = *reinterpret_cast<const bf16x8*>(Bm + (size_t)(bn + r) * Kdim + k0 + schunk * 8);
            int c = (schunk ^ (r & 7)) * 16;  // XOR swizzle (T2)
            *reinterpret_cast<bf16x8*>((char*)As + r * 128 + c) = av;
            *reinterpret_cast<bf16x8*>((char*)Bs + r * 128 + c) = bv;
        }
        __syncthreads();
        #pragma unroll
        for (int s = 0; s < 2; ++s) {
            bf16x8 af[4], bg[4];
            #pragma unroll
            for (int m = 0; m < 4; ++m) {
                int row = wr + m * 16 + fr;
                int c = (s * 64 + 16 * fq) ^ ((row & 7) << 4);
                af[m] = *reinterpret_cast<const bf16x8*>((const char*)As + row * 128 + c);
            }
            #pragma unroll
            for (int n = 0; n < 4; ++n) {
                int row = wc + n * 16 + fr;
                int c = (s * 64 + 16 * fq) ^ ((row & 7) << 4);
                bg[n] = *reinterpret_cast<const bf16x8*>((const char*)Bs + row * 128 + c);
            }
            #pragma unroll
            for (int m = 0; m < 4; ++m)
                #pragma unroll
                for (int n = 0; n < 4; ++n)
                    acc[m][n] = __builtin_amdgcn_mfma_f32_16x16x32_bf16(af[m], bg[n], acc[m][n], 0, 0, 0);
        }
    }
    // epilogue: C/D layout col=lane&15, row=(lane>>4)*4+i
    #pragma unroll
    for (int m = 0; m < 4; ++m) {
        #pragma unroll
        for (int n = 0; n < 4; ++n) {
            int row0 = bm + wr + m * 16 + fq * 4;
            int col = bn + wc + n * 16 + fr;
            #pragma unroll
            for (int i = 0; i < 4; ++i)
                Cm[(size_t)(row0 + i) * Ndim + col] = (OutT)acc[m][n][i];
        }
    }
}

// ---------------- RoPE + pack qkv -> Q,K (B,H,T,D) rope'd, V (B,H,T,D) ----------------
__global__ void rope_pack(const __bf16* __restrict__ qkv,
                          const float* __restrict__ fcos, const float* __restrict__ fsin,
                          __bf16* __restrict__ Q, __bf16* __restrict__ K, __bf16* __restrict__ V)
{
    const int row = blockIdx.x;          // b*T + t
    const int b = row / T_, t = row % T_;
    for (int idx = threadIdx.x; idx < 3 * C_ / 2; idx += blockDim.x) {
        int s = idx / (C_ / 2);
        int rem = idx % (C_ / 2);
        int h = rem >> 6, j = rem & 63;
        const __bf16* src = qkv + (size_t)row * NQKV_ + (s * H_ + h) * D_ + 2 * j;
        float x0 = (float)src[0], x1 = (float)src[1];
        size_t dst = ((size_t)(b * H_ + h) * T_ + t) * D_ + 2 * j;
        if (s == 2) {
            V[dst] = (__bf16)x0; V[dst + 1] = (__bf16)x1;
        } else {
            float c = fcos[t * 64 + j], sn = fsin[t * 64 + j];
            float o0 = x0 * c - x1 * sn, o1 = x0 * sn + x1 * c;
            if (s == 0) { Q[dst] = (__bf16)o0; Q[dst + 1] = (__bf16)o1; }
            else        { K[dst] = (__bf16)o0; K[dst + 1] = (__bf16)o1; }
        }
    }
}

// ---------------- V (BH,T,D) -> Vt (BH,D,T), 64x64 LDS tiles ----------------
__global__ void transpose_v(const __bf16* __restrict__ V, __bf16* __restrict__ Vt) {
    const int bid = blockIdx.x;
    const int per_bh = (T_ / 64) * (D_ / 64);   // 64
    const int bh = bid / per_bh;
    const int rem = bid % per_bh;
    const int t0 = (rem / (D_ / 64)) * 64;
    const int d0 = (rem % (D_ / 64)) * 64;
    __shared__ __align__(16) __bf16 tile[64][72];
    const int tid = threadIdx.x;
    #pragma unroll
    for (int pass = 0; pass < 2; ++pass) {
        int r = pass * 32 + (tid >> 3);
        int ch = tid & 7;
        *reinterpret_cast<bf16x8*>(&tile[r][ch * 8]) =
            *reinterpret_cast<const bf16x8*>(V + ((size_t)bh * T_ + t0 + r) * D_ + d0 + ch * 8);
    }
    __syncthreads();
    #pragma unroll
    for (int pass = 0; pass < 2; ++pass) {
        int dr = pass * 32 + (tid >> 3);
        int ch = tid & 7;
        bf16x8 v;
        #pragma unroll
        for (int e = 0; e < 8; ++e) v[e] = tile[ch * 8 + e][dr];
        *reinterpret_cast<bf16x8*>(Vt + ((size_t)bh * D_ + d0 + dr) * T_ + t0 + ch * 8) = v;
    }
}

// ---------------- flash attention: grid (B*H, T/64), 256 threads ----------------
__global__ __launch_bounds__(256, 2) void attn_fwd(
    const __bf16* __restrict__ Q, const __bf16* __restrict__ K,
    const __bf16* __restrict__ Vt, __bf16* __restrict__ Out)
{
    const int bh = blockIdx.x, qt = blockIdx.y;
    const int tid = threadIdx.x;
    const int wave = tid >> 6, lane = tid & 63;
    const int fr = lane & 15, fq = lane >> 4;
    __shared__ __align__(16) __bf16 Ks[64 * 128];   // [key][d], swizzled 256B rows
    __shared__ __align__(16) __bf16 Vs[128 * 64];   // [d][key], swizzled 128B rows
    __shared__ __align__(16) __bf16 Ps[4][16 * 64]; // per-wave P tile, swizzled 128B rows

    // Q fragments: A-operand row = lane&15, k = 8*(lane>>4)+e ; D=128 -> 4 k-steps
    bf16x8 qf[4];
    {
        const __bf16* qb = Q + ((size_t)bh * T_ + qt * 64 + wave * 16 + fr) * D_;
        #pragma unroll
        for (int s = 0; s < 4; ++s)
            qf[s] = *reinterpret_cast<const bf16x8*>(qb + s * 32 + 8 * fq);
    }
    f32x4 oacc[8] = {};
    float mrow[4], lrow[4];
    #pragma unroll
    for (int i = 0; i < 4; ++i) { mrow[i] = -3.0e38f; lrow[i] = 0.f; }
    const float scale = 0.08838834764831845f;  // 1/sqrt(128)
    char* pb = (char*)&Ps[wave][0];

    for (int kt = 0; kt <= qt; ++kt) {
        __syncthreads();  // previous iteration's K/V reads complete
        {   // stage K tile: 64 rows x 256B; 16 lanes/row, 16 rows/pass
            int r = tid >> 4, ch = tid & 15;
            #pragma unroll
            for (int p = 0; p < 4; ++p) {
                int row = p * 16 + r;
                bf16x8 v = *reinterpret_cast<const bf16x8*>(K + ((size_t)bh * T_ + kt * 64 + row) * D_ + ch * 8);
                int c = (ch ^ (row & 7)) * 16;
                *reinterpret_cast<bf16x8*>((char*)Ks + row * 256 + c) = v;
            }
            // stage V tile: 128 rows x 128B; 8 lanes/row, 32 rows/pass
            int r2 = tid >> 3, ch2 = tid & 7;
            #pragma unroll
            for (int p = 0; p < 4; ++p) {
                int row = p * 32 + r2;
                bf16x8 v = *reinterpret_cast<const bf16x8*>(Vt + ((size_t)bh * D_ + row) * T_ + kt * 64 + ch2 * 8);
                int c = (ch2 ^ (row & 7)) * 16;
                *reinterpret_cast<bf16x8*>((char*)Vs + row * 128 + c) = v;
            }
        }
        __syncthreads();

        // S = Q K^T : 4 col-fragments of 16 keys
        f32x4 sacc[4] = {};
        #pragma unroll
        for (int s = 0; s < 4; ++s) {
            #pragma unroll
            for (int f = 0; f < 4; ++f) {
                int row = f * 16 + fr;
                int c = (s * 64 + 16 * fq) ^ ((row & 7) << 4);
                bf16x8 kf = *reinterpret_cast<const bf16x8*>((const char*)Ks + row * 256 + c);
                sacc[f] = __builtin_amdgcn_mfma_f32_16x16x32_bf16(qf[s], kf, sacc[f], 0, 0, 0);
            }
        }

        // scale + causal mask + online softmax. sacc[f][i] = S[q_local=fq*4+i][key_local=f*16+fr]
        float pm[4];
        #pragma unroll
        for (int i = 0; i < 4; ++i) {
            float mx = -3.0e38f;
            #pragma unroll
            for (int f = 0; f < 4; ++f) {
                float sv = sacc[f][i] * scale;
                if (kt == qt && (f * 16 + fr) > (wave * 16 + fq * 4 + i)) sv = -3.0e38f;
                sacc[f][i] = sv;
                mx = fmaxf(mx, sv);
            }
            pm[i] = mx;
        }
        #pragma unroll
        for (int msk = 1; msk < 16; msk <<= 1)
            #pragma unroll
            for (int i = 0; i < 4; ++i)
                pm[i] = fmaxf(pm[i], __shfl_xor(pm[i], msk, 64));
        float alpha[4], rs[4];
        #pragma unroll
        for (int i = 0; i < 4; ++i) {
            float mn = fmaxf(mrow[i], pm[i]);
            alpha[i] = __expf(mrow[i] - mn);
            mrow[i] = mn;
            rs[i] = 0.f;
        }
        #pragma unroll
        for (int f = 0; f < 4; ++f)
            #pragma unroll
            for (int i = 0; i < 4; ++i) {
                float p = __expf(sacc[f][i] - mrow[i]);
                sacc[f][i] = p;
                rs[i] += p;
            }
        #pragma unroll
        for (int msk = 1; msk < 16; msk <<= 1)
            #pragma unroll
            for (int i = 0; i < 4; ++i)
                rs[i] += __shfl_xor(rs[i], msk, 64);
        #pragma unroll
        for (int i = 0; i < 4; ++i) lrow[i] = lrow[i] * alpha[i] + rs[i];
        #pragma unroll
        for (int n = 0; n < 8; ++n)
            #pragma unroll
            for (int i = 0; i < 4; ++i) oacc[n][i] *= alpha[i];

        // write P (bf16) to per-wave swizzled LDS to re-layout for PV A-operand
        #pragma unroll
        for (int f = 0; f < 4; ++f)
            #pragma unroll
            for (int i = 0; i < 4; ++i) {
                int r = fq * 4 + i;
                int bc = ((f * 16 + fr) * 2) ^ ((r & 7) << 4);
                *reinterpret_cast<__bf16*>(pb + r * 128 + bc) = (__bf16)sacc[f][i];
            }
        asm volatile("s_waitcnt lgkmcnt(0)" ::: "memory");

        // O += P V : A=P[16x64], B=Vs[key][d] via Vt layout
        #pragma unroll
        for (int ks = 0; ks < 2; ++ks) {
            int cp = (ks * 64 + 16 * fq) ^ ((fr & 7) << 4);
            bf16x8 pf = *reinterpret_cast<const bf16x8*>(pb + fr * 128 + cp);
            #pragma unroll
            for (int n = 0; n < 8; ++n) {
                int d = n * 16 + fr;
                int cv = (ks * 64 + 16 * fq) ^ ((d & 7) << 4);
                bf16x8 vf = *reinterpret_cast<const bf16x8*>((const char*)Vs + d * 128 + cv);
                oacc[n] = __builtin_amdgcn_mfma_f32_16x16x32_bf16(pf, vf, oacc[n], 0, 0, 0);
            }
        }
    }

    // epilogue: Out (B,T,H*D) bf16
    const int b = bh >> 4, h = bh & 15;
    #pragma unroll
    for (int n = 0; n < 8; ++n) {
        int d = n * 16 + fr;
        #pragma unroll
        for (int i = 0; i < 4; ++i) {
            int tg = qt * 64 + wave * 16 + fq * 4 + i;
            Out[((size_t)b * T_ + tg) * C_ + h * D_ + d] = (__bf16)(oacc[n][i] / lrow[i]);
        }
    }
}

// ---------------- launch ----------------
extern "C" void kernel_launch(void* const* d_in, const int* in_sizes, int n_in,
                              void* d_out, int out_size, void* d_ws, size_t ws_size,
                              hipStream_t stream) {
    const float* x = (const float*)d_in[0];
    const float* w_qkv = (const float*)d_in[1];
    const float* w_proj = (const float*)d_in[2];
    const float* fcos = (const float*)d_in[3];
    const float* fsin = (const float*)d_in[4];
    float* out = (float*)d_out;

    char* ws = (char*)d_ws;
    size_t o = 0;
    __bf16* xb     = (__bf16*)(ws + o); o += (size_t)M_ * C_ * 2;      // 16.8 MB
    __bf16* wqkvb  = (__bf16*)(ws + o); o += (size_t)NQKV_ * C_ * 2;   // 25.2 MB
    __bf16* wprojb = (__bf16*)(ws + o); o += (size_t)C_ * C_ * 2;      // 8.4 MB
    __bf16* qkvb   = (__bf16*)(ws + o); o += (size_t)M_ * NQKV_ * 2;   // 50.3 MB
    __bf16* Qb     = (__bf16*)(ws + o); o += (size_t)M_ * C_ * 2;      // 16.8 MB
    __bf16* Kb     = (__bf16*)(ws + o); o += (size_t)M_ * C_ * 2;      // 16.8 MB
    __bf16* Vb     = wqkvb;   // alias: w_qkv bf16 dead after QKV GEMM
    __bf16* Vtb    = xb;      // alias: x bf16 dead after QKV GEMM
    __bf16* attnb  = qkvb;    // alias: qkv dead after rope_pack

    cvt_kernel<<<2048, 256, 0, stream>>>(x, xb, M_ * C_ / 4);
    cvt_kernel<<<2048, 256, 0, stream>>>(w_qkv, wqkvb, NQKV_ * C_ / 4);
    cvt_kernel<<<2048, 256, 0, stream>>>(w_proj, wprojb, C_ * C_ / 4);
    gemm_bt<__bf16><<<(M_ / 128) * (NQKV_ / 128), 256, 0, stream>>>(xb, wqkvb, qkvb, M_, NQKV_, C_);
    rope_pack<<<M_, 256, 0, stream>>>(qkvb, fcos, fsin, Qb, Kb, Vb);
    transpose_v<<<B_ * H_ * (T_ / 64) * (D_ / 64), 256, 0, stream>>>(Vb, Vtb);
    attn_fwd<<<dim3(B_ * H_, T_ / 64), 256, 0, stream>>>(Qb, Kb, Vtb, attnb);
    gemm_bt<float><<<(M_ / 128) * (C_ / 128), 256, 0, stream>>>(attnb, wprojb, out, M_, C_, C_);
}

// Round 2
// 409.286 us; speedup vs baseline: 1.0923x; 1.0923x over previous
//
#include <hip/hip_runtime.h>
#include <hip/hip_bf16.h>

typedef float f32x4 __attribute__((ext_vector_type(4)));
typedef __bf16 bf16x8 __attribute__((ext_vector_type(8)));
typedef __bf16 bf16x4 __attribute__((ext_vector_type(4)));

constexpr int B_ = 2, T_ = 2048, C_ = 2048, H_ = 16, D_ = 128;
constexpr int M_ = B_ * T_;        // 4096
constexpr int NQKV_ = 3 * C_;      // 6144

__device__ __forceinline__ void gload_lds16(const void* g, void* l) {
    __builtin_amdgcn_global_load_lds(
        (const __attribute__((address_space(1))) unsigned int*)g,
        (__attribute__((address_space(3))) unsigned int*)l,
        16, 0, 0);
}

// ---------------- fp32 -> bf16 convert (vectorized) ----------------
__global__ void cvt_kernel(const float* __restrict__ in, __bf16* __restrict__ out, int n4) {
    int i = blockIdx.x * blockDim.x + threadIdx.x;
    int stride = gridDim.x * blockDim.x;
    for (; i < n4; i += stride) {
        float4 v = reinterpret_cast<const float4*>(in)[i];
        bf16x4 o;
        o[0] = (__bf16)v.x; o[1] = (__bf16)v.y; o[2] = (__bf16)v.z; o[3] = (__bf16)v.w;
        reinterpret_cast<bf16x4*>(out)[i] = o;
    }
}

// ---------------- GEMM (m97 structure): C[M,N] = A[M,K] * B[N,K]^T ----------------
template <typename OutT>
__global__ __launch_bounds__(256, 3) void gemm_bt(
    const __bf16* __restrict__ A, const __bf16* __restrict__ Bm,
    OutT* __restrict__ Cm, int Mdim, int Ndim, int Kdim)
{
    __shared__ __align__(16) __bf16 As[128 * 64];
    __shared__ __align__(16) __bf16 Bs[128 * 64];
    const int tid = threadIdx.x;
    const int wave = tid >> 6, lane = tid & 63;
    const int fr = lane & 15, fq = lane >> 4;
    const int nbx = Ndim >> 7;
    const int bm = (blockIdx.x / nbx) << 7;
    const int bn = (blockIdx.x % nbx) << 7;
    const int wr = (wave >> 1) * 64, wc = (wave & 1) * 64;
    f32x4 acc[4][4] = {};
    // staging: wave w covers rows 32w..32w+31 (4 x 1KB loads, 8 rows each)
    const int srow = (wave << 5) + (lane >> 3);
    const int sch = lane & 7;
    const __bf16* Ag = A + (size_t)(bm + srow) * Kdim + sch * 8;
    const __bf16* Bg = Bm + (size_t)(bn + srow) * Kdim + sch * 8;

    for (int k0 = 0; k0 < Kdim; k0 += 64) {
        __syncthreads();   // previous tile's reads complete
        #pragma unroll
        for (int p = 0; p < 4; ++p) {
            gload_lds16(Ag + (size_t)(8 * p) * Kdim + k0, (char*)As + (wave * 32 + 8 * p) * 128);
            gload_lds16(Bg + (size_t)(8 * p) * Kdim + k0, (char*)Bs + (wave * 32 + 8 * p) * 128);
        }
        __syncthreads();   // compiler drains vmcnt(0) here
        #pragma unroll
        for (int s = 0; s < 2; ++s) {
            bf16x8 af[4], bg[4];
            #pragma unroll
            for (int m = 0; m < 4; ++m)
                af[m] = *reinterpret_cast<const bf16x8*>((const char*)As + (wr + m * 16 + fr) * 128 + s * 64 + fq * 16);
            #pragma unroll
            for (int n = 0; n < 4; ++n)
                bg[n] = *reinterpret_cast<const bf16x8*>((const char*)Bs + (wc + n * 16 + fr) * 128 + s * 64 + fq * 16);
            #pragma unroll
            for (int m = 0; m < 4; ++m)
                #pragma unroll
                for (int n = 0; n < 4; ++n)
                    acc[m][n] = __builtin_amdgcn_mfma_f32_16x16x32_bf16(af[m], bg[n], acc[m][n], 0, 0, 0);
        }
    }
    #pragma unroll
    for (int m = 0; m < 4; ++m) {
        #pragma unroll
        for (int n = 0; n < 4; ++n) {
            int row0 = bm + wr + m * 16 + fq * 4;
            int col = bn + wc + n * 16 + fr;
            #pragma unroll
            for (int i = 0; i < 4; ++i)
                Cm[(size_t)(row0 + i) * Ndim + col] = (OutT)acc[m][n][i];
        }
    }
}

// ---------------- RoPE + pack qkv -> Q,K (B,H,T,D) rope'd, V (B,H,T,D); vectorized ----------------
__global__ void rope_pack(const __bf16* __restrict__ qkv,
                          const float* __restrict__ fcos, const float* __restrict__ fsin,
                          __bf16* __restrict__ Q, __bf16* __restrict__ K, __bf16* __restrict__ V)
{
    const int row = blockIdx.x;              // b*T + t
    const int b = row >> 11, t = row & (T_ - 1);
    const int tid = threadIdx.x;             // 256
    const int h = tid >> 4;                  // head
    const int jq = tid & 15;                 // 8-elem group within head
    const float4 c4 = *reinterpret_cast<const float4*>(fcos + t * 64 + jq * 4);
    const float4 s4 = *reinterpret_cast<const float4*>(fsin + t * 64 + jq * 4);
    const float cc[4] = {c4.x, c4.y, c4.z, c4.w};
    const float ss[4] = {s4.x, s4.y, s4.z, s4.w};
    const __bf16* src = qkv + (size_t)row * NQKV_ + h * D_ + jq * 8;
    const size_t doff = ((size_t)(b * H_ + h) * T_ + t) * D_ + jq * 8;
    #pragma unroll
    for (int s = 0; s < 3; ++s) {
        bf16x8 v = *reinterpret_cast<const bf16x8*>(src + s * C_);
        bf16x8 o;
        if (s == 2) {
            o = v;
        } else {
            #pragma unroll
            for (int e = 0; e < 4; ++e) {
                float x0 = (float)v[2 * e], x1 = (float)v[2 * e + 1];
                o[2 * e]     = (__bf16)(x0 * cc[e] - x1 * ss[e]);
                o[2 * e + 1] = (__bf16)(x0 * ss[e] + x1 * cc[e]);
            }
        }
        __bf16* dst = (s == 0) ? Q : ((s == 1) ? K : V);
        *reinterpret_cast<bf16x8*>(dst + doff) = o;
    }
}

// ---------------- V (BH,T,D) -> Vt (BH,D,T), 64x64 LDS tiles ----------------
__global__ void transpose_v(const __bf16* __restrict__ V, __bf16* __restrict__ Vt) {
    const int bid = blockIdx.x;
    const int per_bh = (T_ / 64) * (D_ / 64);
    const int bh = bid / per_bh;
    const int rem = bid % per_bh;
    const int t0 = (rem / (D_ / 64)) * 64;
    const int d0 = (rem % (D_ / 64)) * 64;
    __shared__ __align__(16) __bf16 tile[64][72];
    const int tid = threadIdx.x;
    #pragma unroll
    for (int pass = 0; pass < 2; ++pass) {
        int r = pass * 32 + (tid >> 3);
        int ch = tid & 7;
        *reinterpret_cast<bf16x8*>(&tile[r][ch * 8]) =
            *reinterpret_cast<const bf16x8*>(V + ((size_t)bh * T_ + t0 + r) * D_ + d0 + ch * 8);
    }
    __syncthreads();
    #pragma unroll
    for (int pass = 0; pass < 2; ++pass) {
        int dr = pass * 32 + (tid >> 3);
        int ch = tid & 7;
        bf16x8 v;
        #pragma unroll
        for (int e = 0; e < 8; ++e) v[e] = tile[ch * 8 + e][dr];
        *reinterpret_cast<bf16x8*>(Vt + ((size_t)bh * D_ + d0 + dr) * T_ + t0 + ch * 8) = v;
    }
}

// ---------------- flash attention: QBLK=128, 4 waves x 32 rows, KVBLK=64, swapped QK^T ----------------
__global__ __launch_bounds__(256, 2) void attn_fwd(
    const __bf16* __restrict__ Q, const __bf16* __restrict__ K,
    const __bf16* __restrict__ Vt, __bf16* __restrict__ Out)
{
    const int bh = blockIdx.x;
    const int qt = (T_ / 128 - 1) - blockIdx.y;   // long blocks first
    const int tid = threadIdx.x;
    const int wave = tid >> 6, lane = tid & 63;
    const int fr = lane & 15, fq = lane >> 4;
    __shared__ __align__(16) __bf16 Ks[64 * 128];    // [key][d], source-pre-swizzled
    __shared__ __align__(16) __bf16 Vs[128 * 64];    // [d][key], source-pre-swizzled
    __shared__ __align__(16) __bf16 Ps[4][32 * 64];  // per-wave P, swizzled

    const int q0 = qt * 128 + wave * 32;
    // Q as B-operand fragments: lane holds Q[q=q0+m*16+fr][k=ks*32+8*fq+e]
    bf16x8 qf[2][4];
    #pragma unroll
    for (int m = 0; m < 2; ++m)
        #pragma unroll
        for (int ks = 0; ks < 4; ++ks)
            qf[m][ks] = *reinterpret_cast<const bf16x8*>(
                Q + ((size_t)bh * T_ + q0 + m * 16 + fr) * D_ + ks * 32 + 8 * fq);

    f32x4 oacc[2][8] = {};
    float mrow[2] = {-3.0e38f, -3.0e38f}, lrow[2] = {0.f, 0.f};
    const float scale = 0.08838834764831845f;  // 1/sqrt(128)
    char* pb = (char*)&Ps[wave][0];
    const int qmax = q0 + 31;
    const int ktmax = 2 * qt + 1;
    const int kr = lane >> 4, kch = lane & 15;   // K staging: 4 rows/1KB load
    const int vr = lane >> 3, vch = lane & 7;    // V staging: 8 rows/1KB load

    for (int kt = 0; kt <= ktmax; ++kt) {
        __syncthreads();
        // stage K tile (64x256B): wave w rows 16w..16w+15; swizzle folded into SOURCE addr
        #pragma unroll
        for (int p = 0; p < 4; ++p) {
            int row = 16 * wave + 4 * p + kr;
            gload_lds16(K + ((size_t)bh * T_ + kt * 64 + row) * D_ + ((kch ^ (row & 7)) << 3),
                        (char*)Ks + (16 * wave + 4 * p) * 256);
        }
        // stage V tile (128x128B): wave w rows 32w..32w+31
        #pragma unroll
        for (int p = 0; p < 4; ++p) {
            int row = 32 * wave + 8 * p + vr;
            gload_lds16(Vt + ((size_t)bh * D_ + row) * T_ + kt * 64 + ((vch ^ (row & 7)) << 3),
                        (char*)Vs + (32 * wave + 8 * p) * 128);
        }
        __syncthreads();
        if (kt * 64 > qmax) continue;   // fully masked for this wave (barriers already done)

        // S^T = K Q^T : lane holds S[key=kt*64+f*16+fq*4+i][q=q0+m*16+fr]
        f32x4 sacc[2][4] = {};
        __builtin_amdgcn_s_setprio(1);
        #pragma unroll
        for (int ks = 0; ks < 4; ++ks) {
            #pragma unroll
            for (int f = 0; f < 4; ++f) {
                int row = f * 16 + fr;
                bf16x8 kf = *reinterpret_cast<const bf16x8*>(
                    (const char*)Ks + row * 256 + (((ks * 4 + fq) ^ (fr & 7)) << 4));
                sacc[0][f] = __builtin_amdgcn_mfma_f32_16x16x32_bf16(kf, qf[0][ks], sacc[0][f], 0, 0, 0);
                sacc[1][f] = __builtin_amdgcn_mfma_f32_16x16x32_bf16(kf, qf[1][ks], sacc[1][f], 0, 0, 0);
            }
        }
        __builtin_amdgcn_s_setprio(0);

        const bool diag = (kt >= 2 * qt);
        #pragma unroll
        for (int m = 0; m < 2; ++m) {
            const int qg = q0 + m * 16 + fr;
            const int r = m * 16 + fr;
            float mx = -3.0e38f;
            #pragma unroll
            for (int f = 0; f < 4; ++f)
                #pragma unroll
                for (int i = 0; i < 4; ++i) {
                    float sv = sacc[m][f][i] * scale;
                    if (diag && (kt * 64 + f * 16 + fq * 4 + i) > qg) sv = -3.0e38f;
                    sacc[m][f][i] = sv;
                    mx = fmaxf(mx, sv);
                }
            mx = fmaxf(mx, __shfl_xor(mx, 16, 64));
            mx = fmaxf(mx, __shfl_xor(mx, 32, 64));
            float mn = fmaxf(mrow[m], mx);
            float al = __expf(mrow[m] - mn);
            mrow[m] = mn;
            float rs = 0.f;
            #pragma unroll
            for (int f = 0; f < 4; ++f) {
                bf16x4 pv;
                #pragma unroll
                for (int i = 0; i < 4; ++i) {
                    float p = __expf(sacc[m][f][i] - mn);
                    rs += p;
                    pv[i] = (__bf16)p;
                }
                *reinterpret_cast<bf16x4*>(pb + r * 128 + ((f * 32 + fq * 8) ^ ((fr & 7) << 4))) = pv;
            }
            rs += __shfl_xor(rs, 16, 64);
            rs += __shfl_xor(rs, 32, 64);
            lrow[m] = lrow[m] * al + rs;
            float av[4];
            #pragma unroll
            for (int i = 0; i < 4; ++i) av[i] = __shfl(al, fq * 4 + i, 16);
            #pragma unroll
            for (int n = 0; n < 8; ++n)
                #pragma unroll
                for (int i = 0; i < 4; ++i) oacc[m][n][i] *= av[i];
        }

        // O += P V
        __builtin_amdgcn_s_setprio(1);
        #pragma unroll
        for (int ks = 0; ks < 2; ++ks) {
            bf16x8 pa[2];
            #pragma unroll
            for (int m = 0; m < 2; ++m) {
                int r = m * 16 + fr;
                pa[m] = *reinterpret_cast<const bf16x8*>(pb + r * 128 + ((ks * 64 + fq * 16) ^ ((fr & 7) << 4)));
            }
            #pragma unroll
            for (int n = 0; n < 8; ++n) {
                int d = n * 16 + fr;
                bf16x8 vf = *reinterpret_cast<const bf16x8*>(
                    (const char*)Vs + d * 128 + (((ks * 4 + fq) ^ (fr & 7)) << 4));
                oacc[0][n] = __builtin_amdgcn_mfma_f32_16x16x32_bf16(pa[0], vf, oacc[0][n], 0, 0, 0);
                oacc[1][n] = __builtin_amdgcn_mfma_f32_16x16x32_bf16(pa[1], vf, oacc[1][n], 0, 0, 0);
            }
        }
        __builtin_amdgcn_s_setprio(0);
    }

    // epilogue: Out (B,T,H*D) bf16; O rows per lane = fq*4+i, col d = n*16+fr
    const int b = bh >> 4, h = bh & 15;
    #pragma unroll
    for (int m = 0; m < 2; ++m) {
        float linv[4];
        #pragma unroll
        for (int i = 0; i < 4; ++i) linv[i] = 1.0f / __shfl(lrow[m], fq * 4 + i, 16);
        #pragma unroll
        for (int n = 0; n < 8; ++n) {
            int d = n * 16 + fr;
            #pragma unroll
            for (int i = 0; i < 4; ++i) {
                int tg = qt * 128 + wave * 32 + m * 16 + fq * 4 + i;
                Out[((size_t)b * T_ + tg) * C_ + h * D_ + d] = (__bf16)(oacc[m][n][i] * linv[i]);
            }
        }
    }
}

// ---------------- launch ----------------
extern "C" void kernel_launch(void* const* d_in, const int* in_sizes, int n_in,
                              void* d_out, int out_size, void* d_ws, size_t ws_size,
                              hipStream_t stream) {
    const float* x = (const float*)d_in[0];
    const float* w_qkv = (const float*)d_in[1];
    const float* w_proj = (const float*)d_in[2];
    const float* fcos = (const float*)d_in[3];
    const float* fsin = (const float*)d_in[4];
    float* out = (float*)d_out;

    char* ws = (char*)d_ws;
    size_t o = 0;
    __bf16* xb     = (__bf16*)(ws + o); o += (size_t)M_ * C_ * 2;
    __bf16* wqkvb  = (__bf16*)(ws + o); o += (size_t)NQKV_ * C_ * 2;
    __bf16* wprojb = (__bf16*)(ws + o); o += (size_t)C_ * C_ * 2;
    __bf16* qkvb   = (__bf16*)(ws + o); o += (size_t)M_ * NQKV_ * 2;
    __bf16* Qb     = (__bf16*)(ws + o); o += (size_t)M_ * C_ * 2;
    __bf16* Kb     = (__bf16*)(ws + o); o += (size_t)M_ * C_ * 2;
    __bf16* Vb     = wqkvb;   // alias: w_qkv bf16 dead after QKV GEMM
    __bf16* Vtb    = xb;      // alias: x bf16 dead after QKV GEMM
    __bf16* attnb  = qkvb;    // alias: qkv dead after rope_pack

    cvt_kernel<<<2048, 256, 0, stream>>>(x, xb, M_ * C_ / 4);
    cvt_kernel<<<2048, 256, 0, stream>>>(w_qkv, wqkvb, NQKV_ * C_ / 4);
    cvt_kernel<<<2048, 256, 0, stream>>>(w_proj, wprojb, C_ * C_ / 4);
    gemm_bt<__bf16><<<(M_ / 128) * (NQKV_ / 128), 256, 0, stream>>>(xb, wqkvb, qkvb, M_, NQKV_, C_);
    rope_pack<<<M_, 256, 0, stream>>>(qkvb, fcos, fsin, Qb, Kb, Vb);
    transpose_v<<<B_ * H_ * (T_ / 64) * (D_ / 64), 256, 0, stream>>>(Vb, Vtb);
    attn_fwd<<<dim3(B_ * H_, T_ / 128), 256, 0, stream>>>(Qb, Kb, Vtb, attnb);
    gemm_bt<float><<<(M_ / 128) * (C_ / 128), 256, 0, stream>>>(attnb, wprojb, out, M_, C_, C_);
}